// Round 20
// baseline (536.729 us; speedup 1.0000x reference)
//
#include <hip/hip_runtime.h>

// r20 = r19 + octo-edge eighth-wave k_agg: 8 lanes x uint4 (8 bf16 feats)
// per edge -> 8 edges in flight per gather round (vs 4), same bytes, half
// the loop trips. 8 accs/lane, shfl_xor(8/16/32) combine, lanes 0-7 store.

typedef unsigned int uint;
typedef unsigned short ushort;
typedef __attribute__((ext_vector_type(8))) short bf16x8;
typedef __attribute__((ext_vector_type(4))) float f32x4;

__device__ __forceinline__ uint f2bf(float a) {     // RNE f32->bf16 (finite)
    uint u = __float_as_uint(a);
    return (u + 0x7fffu + ((u >> 16) & 1u)) >> 16;
}
__device__ __forceinline__ float bflo(uint p) { return __uint_as_float(p << 16); }
__device__ __forceinline__ float bfhi(uint p) { return __uint_as_float(p & 0xffff0000u); }
__device__ __forceinline__ float b2f16(ushort u) { return __uint_as_float((uint)u << 16); }

// ---------------- weight pre-pack into MFMA B-fragment layout ----------------
__device__ __forceinline__ void packOne(const float* W, int C, int KS,
                                        ushort* dst, int o) {
    int j = o & 7, lane = (o >> 3) & 63, f = o >> 9;
    int ks = f % KS, ct = f / KS;
    int row = 32 * ks + 8 * (lane >> 4) + j;
    int col = ct * 16 + (lane & 15);
    dst[o] = (ushort)f2bf(W[row * C + col]);
}

__global__ void k_pack(const float* __restrict__ faW1, const float* __restrict__ faW2,
                       const float* __restrict__ projW, const float* __restrict__ gatW,
                       const float* __restrict__ oW1, const float* __restrict__ oW2,
                       ushort* __restrict__ pA, ushort* __restrict__ pB,
                       ushort* __restrict__ pC, ushort* __restrict__ pG,
                       ushort* __restrict__ pO1u, ushort* __restrict__ pOW2) {
    int i = blockIdx.x * blockDim.x + threadIdx.x;
    if (i < 8192) packOne(faW1, 64, 4, pA, i);
    else if (i < 16384) packOne(faW2, 128, 2, pB, i - 8192);
    else if (i < 24576) packOne(projW, 64, 4, pC, i - 16384);
    else if (i < 36864) {
        int o = i - 24576; int l = o >> 12;
        packOne(gatW + l * 4096, 64, 2, pG + l * 4096, o & 4095);
    } else if (i < 40960) packOne(oW1, 64, 2, pO1u, i - 36864);   // rows 0..63
    else if (i < 43008) packOne(oW2, 32, 2, pOW2, i - 40960);
}

// -------- fused stage 1: MFMA MLP+z0 || (deg + bucket fill) || prep ----------
__global__ void __launch_bounds__(256)
k_fused1(const float* __restrict__ x,
         const ushort* __restrict__ pA, const float* __restrict__ fab1,
         const ushort* __restrict__ pB, const float* __restrict__ fab2,
         const ushort* __restrict__ pC, const float* __restrict__ projb,
         const ushort* __restrict__ pWz0,
         const float* __restrict__ asrc, const float* __restrict__ adst,
         uint* __restrict__ zbuf, float* __restrict__ es, float* __restrict__ ed,
         int N,
         const int* __restrict__ ei, int E,
         float* __restrict__ deg, int* __restrict__ cursor, int* __restrict__ esrc,
         const float* __restrict__ seW2, const float* __restrict__ seb2,
         const float* __restrict__ oW1, const float* __restrict__ ob1,
         float* __restrict__ M2, float* __restrict__ b2f, ushort* __restrict__ pM2f,
         int gMlp, int gEdge) {
    __shared__ ushort S[4][16][136];                   // bf16 staging, 17.4KB
    int bid = blockIdx.x;
    if (bid < gMlp) {
        int wave = threadIdx.x >> 6, lane = threadIdx.x & 63;
        int qg = lane >> 4, lr = lane & 15;
        int n0w = (bid * 4 + wave) * 16;
        int nr = n0w + lr; if (nr >= N) nr = N - 1;
        const float* xr = x + (size_t)nr * 128;
        ushort (*T)[136] = S[wave];
        const bf16x8* fA = reinterpret_cast<const bf16x8*>(pA);
        const bf16x8* fB = reinterpret_cast<const bf16x8*>(pB);
        const bf16x8* fC = reinterpret_cast<const bf16x8*>(pC);
        const bf16x8* fZ = reinterpret_cast<const bf16x8*>(pWz0);

        // ---- stage A: T = relu(X @ faW1 + b1) ----
        bf16x8 afr[4];
#pragma unroll
        for (int ks = 0; ks < 4; ++ks) {
            const float* p = xr + 32 * ks + 8 * qg;
            float4 v0 = *reinterpret_cast<const float4*>(p);
            float4 v1 = *reinterpret_cast<const float4*>(p + 4);
            bf16x8 a;
            a[0] = (short)f2bf(v0.x); a[1] = (short)f2bf(v0.y);
            a[2] = (short)f2bf(v0.z); a[3] = (short)f2bf(v0.w);
            a[4] = (short)f2bf(v1.x); a[5] = (short)f2bf(v1.y);
            a[6] = (short)f2bf(v1.z); a[7] = (short)f2bf(v1.w);
            afr[ks] = a;
        }
        {
            f32x4 acc[4] = {{0,0,0,0},{0,0,0,0},{0,0,0,0},{0,0,0,0}};
#pragma unroll
            for (int ct = 0; ct < 4; ++ct)
#pragma unroll
                for (int ks = 0; ks < 4; ++ks)
                    acc[ct] = __builtin_amdgcn_mfma_f32_16x16x32_bf16(
                        afr[ks], fA[(ct * 4 + ks) * 64 + lane], acc[ct], 0, 0, 0);
#pragma unroll
            for (int ct = 0; ct < 4; ++ct) {
                float b1v = fab1[ct * 16 + lr];
#pragma unroll
                for (int r = 0; r < 4; ++r)
                    T[qg * 4 + r][ct * 16 + lr] =
                        (ushort)f2bf(fmaxf(acc[ct][r] + b1v, 0.f));
            }
        }
        __syncthreads();

        // ---- stage B: F = T @ faW2 + b2 ----
        bf16x8 bfr[2];
#pragma unroll
        for (int ks = 0; ks < 2; ++ks)
            bfr[ks] = *reinterpret_cast<const bf16x8*>(&T[lr][32 * ks + 8 * qg]);
        __syncthreads();
        {
            f32x4 acc[8] = {{0,0,0,0},{0,0,0,0},{0,0,0,0},{0,0,0,0},
                            {0,0,0,0},{0,0,0,0},{0,0,0,0},{0,0,0,0}};
#pragma unroll
            for (int ct = 0; ct < 8; ++ct)
#pragma unroll
                for (int ks = 0; ks < 2; ++ks)
                    acc[ct] = __builtin_amdgcn_mfma_f32_16x16x32_bf16(
                        bfr[ks], fB[(ct * 2 + ks) * 64 + lane], acc[ct], 0, 0, 0);
#pragma unroll
            for (int ct = 0; ct < 8; ++ct) {
                float b2v = fab2[ct * 16 + lr];
#pragma unroll
                for (int r = 0; r < 4; ++r)
                    T[qg * 4 + r][ct * 16 + lr] = (ushort)f2bf(acc[ct][r] + b2v);
            }
        }
        __syncthreads();

        // ---- stage C: H = (X * sigmoid(F)) @ projW + projb -> T (bf16) ----
        bf16x8 cfr[4];
#pragma unroll
        for (int ks = 0; ks < 4; ++ks) {
            const ushort* pf = &T[lr][32 * ks + 8 * qg];
            const float* px = xr + 32 * ks + 8 * qg;
            float4 x0 = *reinterpret_cast<const float4*>(px);
            float4 x1 = *reinterpret_cast<const float4*>(px + 4);
            bf16x8 a;
            a[0] = (short)f2bf(x0.x / (1.f + __expf(-b2f16(pf[0]))));
            a[1] = (short)f2bf(x0.y / (1.f + __expf(-b2f16(pf[1]))));
            a[2] = (short)f2bf(x0.z / (1.f + __expf(-b2f16(pf[2]))));
            a[3] = (short)f2bf(x0.w / (1.f + __expf(-b2f16(pf[3]))));
            a[4] = (short)f2bf(x1.x / (1.f + __expf(-b2f16(pf[4]))));
            a[5] = (short)f2bf(x1.y / (1.f + __expf(-b2f16(pf[5]))));
            a[6] = (short)f2bf(x1.z / (1.f + __expf(-b2f16(pf[6]))));
            a[7] = (short)f2bf(x1.w / (1.f + __expf(-b2f16(pf[7]))));
            cfr[ks] = a;
        }
        __syncthreads();                               // F reads done before H write
        {
            f32x4 acc[4] = {{0,0,0,0},{0,0,0,0},{0,0,0,0},{0,0,0,0}};
#pragma unroll
            for (int ct = 0; ct < 4; ++ct)
#pragma unroll
                for (int ks = 0; ks < 4; ++ks)
                    acc[ct] = __builtin_amdgcn_mfma_f32_16x16x32_bf16(
                        cfr[ks], fC[(ct * 4 + ks) * 64 + lane], acc[ct], 0, 0, 0);
#pragma unroll
            for (int ct = 0; ct < 4; ++ct) {
                float pbv = projb[ct * 16 + lr];
#pragma unroll
                for (int r = 0; r < 4; ++r)
                    T[qg * 4 + r][ct * 16 + lr] = (ushort)f2bf(acc[ct][r] + pbv);
            }
        }
        __syncthreads();

        // ---- stage D: z0 = H @ W0 (8 MFMAs), es/ed + bf16 zbuf ----
        bf16x8 hfr[2];
#pragma unroll
        for (int ks = 0; ks < 2; ++ks)
            hfr[ks] = *reinterpret_cast<const bf16x8*>(&T[lr][32 * ks + 8 * qg]);
        __syncthreads();
        {
            f32x4 zacc[4] = {{0,0,0,0},{0,0,0,0},{0,0,0,0},{0,0,0,0}};
#pragma unroll
            for (int ct = 0; ct < 4; ++ct)
#pragma unroll
                for (int ks = 0; ks < 2; ++ks)
                    zacc[ct] = __builtin_amdgcn_mfma_f32_16x16x32_bf16(
                        hfr[ks], fZ[(ct * 2 + ks) * 64 + lane], zacc[ct], 0, 0, 0);
#pragma unroll
            for (int ct = 0; ct < 4; ++ct)
#pragma unroll
                for (int r = 0; r < 4; ++r)
                    T[qg * 4 + r][ct * 16 + lr] = (ushort)f2bf(zacc[ct][r]);
        }
        __syncthreads();
        {
            bf16x8 z0 = *reinterpret_cast<const bf16x8*>(&T[lr][qg * 16]);
            bf16x8 z1 = *reinterpret_cast<const bf16x8*>(&T[lr][qg * 16 + 8]);
            float pe = 0.f, pd = 0.f;
#pragma unroll
            for (int j = 0; j < 8; ++j) {
                float va = b2f16((ushort)z0[j]), vb = b2f16((ushort)z1[j]);
                pe = fmaf(va, asrc[qg * 16 + j], pe);
                pe = fmaf(vb, asrc[qg * 16 + 8 + j], pe);
                pd = fmaf(va, adst[qg * 16 + j], pd);
                pd = fmaf(vb, adst[qg * 16 + 8 + j], pd);
            }
            pe += __shfl_xor(pe, 16, 64); pe += __shfl_xor(pe, 32, 64);
            pd += __shfl_xor(pd, 16, 64); pd += __shfl_xor(pd, 32, 64);
            int n = n0w + lr;
            if (n < N) {
                uint4 u0, u1;
                u0.x = (ushort)z0[0] | ((uint)(ushort)z0[1] << 16);
                u0.y = (ushort)z0[2] | ((uint)(ushort)z0[3] << 16);
                u0.z = (ushort)z0[4] | ((uint)(ushort)z0[5] << 16);
                u0.w = (ushort)z0[6] | ((uint)(ushort)z0[7] << 16);
                u1.x = (ushort)z1[0] | ((uint)(ushort)z1[1] << 16);
                u1.y = (ushort)z1[2] | ((uint)(ushort)z1[3] << 16);
                u1.z = (ushort)z1[4] | ((uint)(ushort)z1[5] << 16);
                u1.w = (ushort)z1[6] | ((uint)(ushort)z1[7] << 16);
                uint* zr8 = zbuf + (size_t)n * 32 + qg * 8;
                *reinterpret_cast<uint4*>(zr8) = u0;
                *reinterpret_cast<uint4*>(zr8 + 4) = u1;
                if (qg == 0) { es[n] = pe; ed[n] = pd; esrc[(size_t)n * 64] = n; }
            }
        }
    } else if (bid < gMlp + gEdge) {
        int e = (bid - gMlp) * blockDim.x + threadIdx.x;
        if (e < E) {
            int s = ei[e], d = ei[E + e];
            atomicAdd(&deg[s], 1.f);
            int p = atomicAdd(&cursor[d], 1);
            esrc[(size_t)d * 64 + 1 + p] = s;
        }
    } else {
        int tid = threadIdx.x;
        for (int o = tid; o < 32 * 64; o += 256) {
            int k = o >> 6, j = o & 63;
            float s = 0.f;
            for (int i = 0; i < 64; ++i)
                s = fmaf(seW2[k * 64 + i], oW1[(64 + i) * 64 + j], s);
            M2[o] = s;
        }
        for (int j = tid; j < 64; j += 256) {
            float s = ob1[j];
            for (int i = 0; i < 64; ++i)
                s = fmaf(seb2[i], oW1[(64 + i) * 64 + j], s);
            b2f[j] = s;
        }
        __syncthreads();
        for (int o = tid; o < 2048; o += 256)
            packOne(M2, 64, 1, pM2f, o);
    }
}

// ---------------- MFMA GAT z (layers 1,2); || infl/scal rider ----------------
__global__ __attribute__((amdgpu_waves_per_eu(4, 4))) void __launch_bounds__(256)
k_z(const float* __restrict__ hbuf, const ushort* __restrict__ pWz,
    const float* __restrict__ asrc, const float* __restrict__ adst,
    uint* __restrict__ zbuf, float* __restrict__ es, float* __restrict__ ed,
    const float* __restrict__ deg, const float* __restrict__ inflsum,
    float* __restrict__ inflv, unsigned* __restrict__ scal,
    int N, int gZ) {
    int bid = blockIdx.x;
    if (bid >= gZ) {
        int idx = (bid - gZ) * blockDim.x + threadIdx.x;
        float dv = 0.f, iv = 0.f;
        if (idx < N) {
            dv = deg[idx];
            iv = dv > 0.f ? inflsum[idx] / dv : 0.f;
            inflv[idx] = iv;
        }
        float dm = dv, im = iv;
#pragma unroll
        for (int off = 32; off; off >>= 1) {
            dm = fmaxf(dm, __shfl_xor(dm, off, 64));
            im = fmaxf(im, __shfl_xor(im, off, 64));
        }
        if ((threadIdx.x & 63) == 0) {
            atomicMax(scal + 0, __float_as_uint(dm));
            atomicMax(scal + 1, __float_as_uint(im));
        }
        return;
    }
    __shared__ float zt[4][16][68];
    int wave = threadIdx.x >> 6, lane = threadIdx.x & 63;
    int qg = lane >> 4, lr = lane & 15;
    int n0w = (bid * 4 + wave) * 16;
    int nr = n0w + lr; if (nr >= N) nr = N - 1;

    bf16x8 afr[2];
#pragma unroll
    for (int k2 = 0; k2 < 2; ++k2) {
        const float* hp = hbuf + (size_t)nr * 64 + k2 * 32 + qg * 8;
        float4 h0 = *reinterpret_cast<const float4*>(hp);
        float4 h1 = *reinterpret_cast<const float4*>(hp + 4);
        bf16x8 a;
        a[0] = (short)f2bf(h0.x); a[1] = (short)f2bf(h0.y);
        a[2] = (short)f2bf(h0.z); a[3] = (short)f2bf(h0.w);
        a[4] = (short)f2bf(h1.x); a[5] = (short)f2bf(h1.y);
        a[6] = (short)f2bf(h1.z); a[7] = (short)f2bf(h1.w);
        afr[k2] = a;
    }

    const bf16x8* pw = reinterpret_cast<const bf16x8*>(pWz);
    f32x4 acc0 = {0,0,0,0}, acc1 = {0,0,0,0}, acc2 = {0,0,0,0}, acc3 = {0,0,0,0};
#pragma unroll
    for (int k2 = 0; k2 < 2; ++k2) {
        acc0 = __builtin_amdgcn_mfma_f32_16x16x32_bf16(afr[k2], pw[(0 * 2 + k2) * 64 + lane], acc0, 0, 0, 0);
        acc1 = __builtin_amdgcn_mfma_f32_16x16x32_bf16(afr[k2], pw[(1 * 2 + k2) * 64 + lane], acc1, 0, 0, 0);
        acc2 = __builtin_amdgcn_mfma_f32_16x16x32_bf16(afr[k2], pw[(2 * 2 + k2) * 64 + lane], acc2, 0, 0, 0);
        acc3 = __builtin_amdgcn_mfma_f32_16x16x32_bf16(afr[k2], pw[(3 * 2 + k2) * 64 + lane], acc3, 0, 0, 0);
    }

    float (*Z)[68] = zt[wave];
#pragma unroll
    for (int r = 0; r < 4; ++r) {
        Z[qg * 4 + r][0 * 16 + lr] = acc0[r];
        Z[qg * 4 + r][1 * 16 + lr] = acc1[r];
        Z[qg * 4 + r][2 * 16 + lr] = acc2[r];
        Z[qg * 4 + r][3 * 16 + lr] = acc3[r];
    }
    __syncthreads();

    float zr[16];
    const float* zrow = &Z[lr][qg * 16];
#pragma unroll
    for (int q4 = 0; q4 < 4; ++q4) {
        float4 v = *reinterpret_cast<const float4*>(zrow + q4 * 4);
        zr[q4 * 4] = v.x; zr[q4 * 4 + 1] = v.y; zr[q4 * 4 + 2] = v.z; zr[q4 * 4 + 3] = v.w;
    }
    float pe = 0.f, pd = 0.f;
#pragma unroll
    for (int j = 0; j < 16; ++j) {
        pe = fmaf(zr[j], asrc[qg * 16 + j], pe);
        pd = fmaf(zr[j], adst[qg * 16 + j], pd);
    }
    pe += __shfl_xor(pe, 16, 64); pe += __shfl_xor(pe, 32, 64);
    pd += __shfl_xor(pd, 16, 64); pd += __shfl_xor(pd, 32, 64);

    int n = n0w + lr;
    if (n < N) {
        uint4 u0, u1;
        u0.x = f2bf(zr[0]) | (f2bf(zr[1]) << 16);
        u0.y = f2bf(zr[2]) | (f2bf(zr[3]) << 16);
        u0.z = f2bf(zr[4]) | (f2bf(zr[5]) << 16);
        u0.w = f2bf(zr[6]) | (f2bf(zr[7]) << 16);
        u1.x = f2bf(zr[8]) | (f2bf(zr[9]) << 16);
        u1.y = f2bf(zr[10]) | (f2bf(zr[11]) << 16);
        u1.z = f2bf(zr[12]) | (f2bf(zr[13]) << 16);
        u1.w = f2bf(zr[14]) | (f2bf(zr[15]) << 16);
        uint* zr8 = zbuf + (size_t)n * 32 + qg * 8;
        *reinterpret_cast<uint4*>(zr8) = u0;
        *reinterpret_cast<uint4*>(zr8 + 4) = u1;
        if (qg == 0) { es[n] = pe; ed[n] = pd; }
    }
}

// ------ fused GAT aggregation: octo-edge eighth-wave; || inflsum rider -------
__global__ void k_agg(const int* __restrict__ cursor,
                      const int* __restrict__ esrc,
                      const float* __restrict__ es, const float* __restrict__ ed,
                      const uint* __restrict__ zb,
                      const float* __restrict__ b, const float* __restrict__ g,
                      const float* __restrict__ bta, const float* __restrict__ mean,
                      const float* __restrict__ var,
                      float* __restrict__ hbuf, int N,
                      const int* __restrict__ ei, int E,
                      const float* __restrict__ deg, float* __restrict__ inflsum,
                      int gAgg) {
    if (blockIdx.x >= gAgg) {
        int e = (blockIdx.x - gAgg) * blockDim.x + threadIdx.x;
        if (e < E) atomicAdd(&inflsum[ei[e]], deg[ei[E + e]]);
        return;
    }
    int wid  = (blockIdx.x * blockDim.x + threadIdx.x) >> 6;
    int lane = threadIdx.x & 63;
    if (wid >= N) return;
    size_t row0 = (size_t)wid * 64;
    int c    = cursor[wid] + 1;    // +1 self-loop; c <= 64 guaranteed
    float edn = ed[wid];
    int lo = lane & 7, oc = lane >> 3;                 // 8 lanes/edge, 8 edges in flight

    int   sreg = 0;
    float exv  = 0.f;
    if (lane < c) {
        sreg = esrc[row0 + lane];                      // coalesced 256B row
        float e = es[sreg] + edn;
        e = e >= 0.f ? e : 0.2f * e;
        exv = __expf(e);
    }
    float ssum = exv;
#pragma unroll
    for (int off = 32; off; off >>= 1) ssum += __shfl_xor(ssum, off, 64);

    float a0 = 0.f, a1 = 0.f, a2 = 0.f, a3 = 0.f;
    float a4 = 0.f, a5 = 0.f, a6 = 0.f, a7 = 0.f;
    for (int e = oc; e < c; e += 8) {
        int   se = __shfl(sreg, e, 64);
        float we = __shfl(exv, e, 64);
        uint4 p = *reinterpret_cast<const uint4*>(zb + (size_t)se * 32 + lo * 4);
        a0 = fmaf(bflo(p.x), we, a0);
        a1 = fmaf(bfhi(p.x), we, a1);
        a2 = fmaf(bflo(p.y), we, a2);
        a3 = fmaf(bfhi(p.y), we, a3);
        a4 = fmaf(bflo(p.z), we, a4);
        a5 = fmaf(bfhi(p.z), we, a5);
        a6 = fmaf(bflo(p.w), we, a6);
        a7 = fmaf(bfhi(p.w), we, a7);
    }
#pragma unroll
    for (int off = 8; off < 64; off <<= 1) {
        a0 += __shfl_xor(a0, off, 64);
        a1 += __shfl_xor(a1, off, 64);
        a2 += __shfl_xor(a2, off, 64);
        a3 += __shfl_xor(a3, off, 64);
        a4 += __shfl_xor(a4, off, 64);
        a5 += __shfl_xor(a5, off, 64);
        a6 += __shfl_xor(a6, off, 64);
        a7 += __shfl_xor(a7, off, 64);
    }

    if (oc == 0) {                                     // lanes 0-7: feats lo*8..lo*8+7
        float inv = 1.f / ssum;
        float av[8] = {a0, a1, a2, a3, a4, a5, a6, a7};
        float ov[8];
#pragma unroll
        for (int j = 0; j < 8; ++j) {
            int f = lo * 8 + j;
            float sc = g[f] * rsqrtf(var[f] + 1e-5f);
            ov[j] = fmaxf((av[j] * inv + b[f] - mean[f]) * sc + bta[f], 0.f);
        }
        float* hr = hbuf + (size_t)wid * 64 + lo * 8;
        *reinterpret_cast<float4*>(hr) = make_float4(ov[0], ov[1], ov[2], ov[3]);
        *reinterpret_cast<float4*>(hr + 4) = make_float4(ov[4], ov[5], ov[6], ov[7]);
    }
}

// ---------------- MFMA output head: 16 nodes/wave ----------------
__global__ void __launch_bounds__(256)
k_final(const float* __restrict__ hbuf, const float* __restrict__ deg,
        const float* __restrict__ inflv, const unsigned* __restrict__ scal,
        const float* __restrict__ seW1, const float* __restrict__ seb1,
        const ushort* __restrict__ pM2f, const float* __restrict__ b2f,
        const ushort* __restrict__ pO1u, const ushort* __restrict__ pOW2,
        const float* __restrict__ ob2,
        const float* __restrict__ oW3, const float* __restrict__ ob3,
        float* __restrict__ out, int N) {
    __shared__ ushort S[4][16][136];
    int wave = threadIdx.x >> 6, lane = threadIdx.x & 63;
    int qg = lane >> 4, lr = lane & 15;
    int n0w = (blockIdx.x * 4 + wave) * 16;
    int nr = n0w + lr; if (nr >= N) nr = N - 1;
    ushort (*T)[136] = S[wave];

    float degmax  = fmaxf(__uint_as_float(scal[0]), 1.0f);
    float inflmax = fmaxf(__uint_as_float(scal[1]), 1e-12f);
    float nd = deg[nr] / degmax;
    float fl = inflv[nr] / inflmax;

    bf16x8 a0, a1, a2;
#pragma unroll
    for (int ks = 0; ks < 2; ++ks) {
        const float* hp = hbuf + (size_t)nr * 64 + 32 * ks + 8 * qg;
        float4 h0 = *reinterpret_cast<const float4*>(hp);
        float4 h1 = *reinterpret_cast<const float4*>(hp + 4);
        bf16x8 a;
        a[0] = (short)f2bf(h0.x); a[1] = (short)f2bf(h0.y);
        a[2] = (short)f2bf(h0.z); a[3] = (short)f2bf(h0.w);
        a[4] = (short)f2bf(h1.x); a[5] = (short)f2bf(h1.y);
        a[6] = (short)f2bf(h1.z); a[7] = (short)f2bf(h1.w);
        if (ks == 0) a0 = a; else a1 = a;
    }
#pragma unroll
    for (int j = 0; j < 8; ++j) {
        int k = 8 * qg + j;
        float hid = fmaxf(fmaf(nd, seW1[k], fmaf(fl, seW1[64 + k], seb1[k])), 0.f);
        a2[j] = (short)f2bf(hid);
    }

    const bf16x8* fO1 = reinterpret_cast<const bf16x8*>(pO1u);
    const bf16x8* fM2 = reinterpret_cast<const bf16x8*>(pM2f);
    const bf16x8* fW2 = reinterpret_cast<const bf16x8*>(pOW2);

    {
        f32x4 acc[4] = {{0,0,0,0},{0,0,0,0},{0,0,0,0},{0,0,0,0}};
#pragma unroll
        for (int ct = 0; ct < 4; ++ct) {
            acc[ct] = __builtin_amdgcn_mfma_f32_16x16x32_bf16(a0, fO1[(ct * 2 + 0) * 64 + lane], acc[ct], 0, 0, 0);
            acc[ct] = __builtin_amdgcn_mfma_f32_16x16x32_bf16(a1, fO1[(ct * 2 + 1) * 64 + lane], acc[ct], 0, 0, 0);
            acc[ct] = __builtin_amdgcn_mfma_f32_16x16x32_bf16(a2, fM2[ct * 64 + lane], acc[ct], 0, 0, 0);
        }
#pragma unroll
        for (int ct = 0; ct < 4; ++ct) {
            float bv = b2f[ct * 16 + lr];
#pragma unroll
            for (int r = 0; r < 4; ++r)
                T[qg * 4 + r][ct * 16 + lr] =
                    (ushort)f2bf(fmaxf(acc[ct][r] + bv, 0.f));
        }
    }
    __syncthreads();

    bf16x8 b0 = *reinterpret_cast<const bf16x8*>(&T[lr][8 * qg]);
    bf16x8 b1 = *reinterpret_cast<const bf16x8*>(&T[lr][32 + 8 * qg]);
    f32x4 o2a = {0,0,0,0}, o2b = {0,0,0,0};
    o2a = __builtin_amdgcn_mfma_f32_16x16x32_bf16(b0, fW2[0 * 64 + lane], o2a, 0, 0, 0);
    o2a = __builtin_amdgcn_mfma_f32_16x16x32_bf16(b1, fW2[1 * 64 + lane], o2a, 0, 0, 0);
    o2b = __builtin_amdgcn_mfma_f32_16x16x32_bf16(b0, fW2[2 * 64 + lane], o2b, 0, 0, 0);
    o2b = __builtin_amdgcn_mfma_f32_16x16x32_bf16(b1, fW2[3 * 64 + lane], o2b, 0, 0, 0);

    float w3a = oW3[lr], w3b = oW3[16 + lr];
    float oba = ob2[lr], obb = ob2[16 + lr];
    float part[4];
#pragma unroll
    for (int r = 0; r < 4; ++r)
        part[r] = fmaxf(o2a[r] + oba, 0.f) * w3a + fmaxf(o2b[r] + obb, 0.f) * w3b;
#pragma unroll
    for (int off = 1; off < 16; off <<= 1) {
#pragma unroll
        for (int r = 0; r < 4; ++r) part[r] += __shfl_xor(part[r], off, 64);
    }
    if (lr == 0) {
        float b3 = ob3[0];
#pragma unroll
        for (int r = 0; r < 4; ++r) {
            int n = n0w + qg * 4 + r;
            if (n < N) out[n] = 1.f / (1.f + __expf(-(part[r] + b3)));
        }
    }
}

// ---------------- launch ----------------
extern "C" void kernel_launch(void* const* d_in, const int* in_sizes, int n_in,
                              void* d_out, int out_size, void* d_ws, size_t ws_size,
                              hipStream_t stream) {
    const float* x     = (const float*)d_in[0];
    const int*   ei    = (const int*)d_in[1];
    const float* faW1  = (const float*)d_in[2];
    const float* fab1  = (const float*)d_in[3];
    const float* faW2  = (const float*)d_in[4];
    const float* fab2  = (const float*)d_in[5];
    const float* projW = (const float*)d_in[6];
    const float* projb = (const float*)d_in[7];
    const float* gatW  = (const float*)d_in[8];
    const float* gatAs = (const float*)d_in[9];
    const float* gatAd = (const float*)d_in[10];
    const float* gatB  = (const float*)d_in[11];
    const float* bnG   = (const float*)d_in[12];
    const float* bnB   = (const float*)d_in[13];
    const float* bnM   = (const float*)d_in[14];
    const float* bnV   = (const float*)d_in[15];
    const float* seW1  = (const float*)d_in[16];
    const float* seb1  = (const float*)d_in[17];
    const float* seW2  = (const float*)d_in[18];
    const float* seb2  = (const float*)d_in[19];
    const float* oW1   = (const float*)d_in[20];
    const float* ob1   = (const float*)d_in[21];
    const float* oW2   = (const float*)d_in[22];
    const float* ob2   = (const float*)d_in[23];
    const float* oW3   = (const float*)d_in[24];
    const float* ob3   = (const float*)d_in[25];
    float* out = (float*)d_out;

    const int N = in_sizes[0] / 128;
    const int E = in_sizes[1] / 2;

    float* ws      = (float*)d_ws;
    float* hbuf    = ws;                               // N*64
    uint*  zbuf    = (uint*)(hbuf + (size_t)N * 64);   // N*32 (bf16 pairs)
    float* es      = (float*)(zbuf + (size_t)N * 32);  // N
    float* ed      = es + N;                           // N
    // ---- zero region (one memset: 3N+8 dwords) ----
    float* deg     = ed + N;                           // N
    float* inflsum = deg + N;                          // N
    unsigned* scal = (unsigned*)(inflsum + N);         // 8
    int* cursor    = (int*)(scal + 8);                 // N
    // ---- end zero region ----
    float* inflv   = (float*)(cursor + N);             // N
    int* esrc      = (int*)(inflv + N);                // N*64 padded buckets
    float* M2      = (float*)(esrc + (size_t)N * 64);  // 32*64
    float* b2f     = M2 + 32 * 64;                     // 64
    ushort* pA   = (ushort*)(b2f + 64);                // 8192
    ushort* pB   = pA + 8192;                          // 8192
    ushort* pC   = pB + 8192;                          // 8192
    ushort* pWz  = pC + 8192;                          // 3*4096
    ushort* pO1u = pWz + 3 * 4096;                     // 4096
    ushort* pOW2 = pO1u + 4096;                        // 2048
    ushort* pM2f = pOW2 + 2048;                        // 2048

    dim3 blk(256);
    int gN    = (N + 255) / 256;
    int gE    = (E + 255) / 256;
    int gM    = (N + 63) / 64;                         // MFMA tiles: 64 nodes/block
    int blkNW = (N * 64 + 255) / 256;                  // wave-per-node (k_agg)

    hipMemsetAsync(deg, 0, ((size_t)3 * N + 8) * sizeof(float), stream);

    // stage 0: pack static MFMA weight fragments
    k_pack<<<168, blk, 0, stream>>>(faW1, faW2, projW, gatW, oW1, oW2,
                                    pA, pB, pC, pWz, pO1u, pOW2);

    // stage 1: MFMA mlp+z0 || (deg + bucket fill) || prep(+M2 frag)
    k_fused1<<<gM + gE + 1, blk, 0, stream>>>(x, pA, fab1, pB, fab2, pC, projb,
                                              pWz, gatAs, gatAd, zbuf, es, ed, N,
                                              ei, E, deg, cursor, esrc,
                                              seW2, seb2, oW1, ob1, M2, b2f, pM2f,
                                              gM, gE);

    for (int l = 0; l < 3; ++l) {
        int aggExtra = (l == 0) ? gE : 0;              // inflsum rider on l==0
        k_agg<<<blkNW + aggExtra, blk, 0, stream>>>(cursor, esrc, es, ed, zbuf,
                                                    gatB + l * 64, bnG + l * 64,
                                                    bnB + l * 64, bnM + l * 64,
                                                    bnV + l * 64, hbuf, N,
                                                    ei, E, deg, inflsum, blkNW);
        if (l < 2) {
            int extra = (l == 0) ? gN : 0;             // infl/scal reduce on first k_z
            k_z<<<gM + extra, blk, 0, stream>>>(hbuf, pWz + (l + 1) * 4096,
                                                gatAs + (l + 1) * 64,
                                                gatAd + (l + 1) * 64,
                                                zbuf, es, ed,
                                                deg, inflsum, inflv, scal, N, gM);
        }
    }

    k_final<<<gM, blk, 0, stream>>>(hbuf, deg, inflv, scal, seW1, seb1,
                                    pM2f, b2f, pO1u, pOW2, ob2, oW3, ob3, out, N);
}

// Round 21
// 505.388 us; speedup vs baseline: 1.0620x; 1.0620x over previous
//
#include <hip/hip_runtime.h>

// r21 = r19 exact (r20's octo-edge k_agg regressed: combine cost tripled
// [24 shfl vs 8] while the gather was already latency-covered at 4 edges
// in flight; quad-edge is the sweet spot). Pipeline summary:
//  k_pack: static MFMA weight fragments
//  k_fused1: MFMA MLP+z0 (16-node tiles) || edge pass (deg + bucket fill) || prep
//  3x { k_agg (quad-edge quarter-wave softmax-aggregate+BN, riders) ; k_z (MFMA) }
//  k_final: MFMA output head.

typedef unsigned int uint;
typedef unsigned short ushort;
typedef __attribute__((ext_vector_type(8))) short bf16x8;
typedef __attribute__((ext_vector_type(4))) float f32x4;

__device__ __forceinline__ uint f2bf(float a) {     // RNE f32->bf16 (finite)
    uint u = __float_as_uint(a);
    return (u + 0x7fffu + ((u >> 16) & 1u)) >> 16;
}
__device__ __forceinline__ float bflo(uint p) { return __uint_as_float(p << 16); }
__device__ __forceinline__ float bfhi(uint p) { return __uint_as_float(p & 0xffff0000u); }
__device__ __forceinline__ float b2f16(ushort u) { return __uint_as_float((uint)u << 16); }

// ---------------- weight pre-pack into MFMA B-fragment layout ----------------
__device__ __forceinline__ void packOne(const float* W, int C, int KS,
                                        ushort* dst, int o) {
    int j = o & 7, lane = (o >> 3) & 63, f = o >> 9;
    int ks = f % KS, ct = f / KS;
    int row = 32 * ks + 8 * (lane >> 4) + j;
    int col = ct * 16 + (lane & 15);
    dst[o] = (ushort)f2bf(W[row * C + col]);
}

__global__ void k_pack(const float* __restrict__ faW1, const float* __restrict__ faW2,
                       const float* __restrict__ projW, const float* __restrict__ gatW,
                       const float* __restrict__ oW1, const float* __restrict__ oW2,
                       ushort* __restrict__ pA, ushort* __restrict__ pB,
                       ushort* __restrict__ pC, ushort* __restrict__ pG,
                       ushort* __restrict__ pO1u, ushort* __restrict__ pOW2) {
    int i = blockIdx.x * blockDim.x + threadIdx.x;
    if (i < 8192) packOne(faW1, 64, 4, pA, i);
    else if (i < 16384) packOne(faW2, 128, 2, pB, i - 8192);
    else if (i < 24576) packOne(projW, 64, 4, pC, i - 16384);
    else if (i < 36864) {
        int o = i - 24576; int l = o >> 12;
        packOne(gatW + l * 4096, 64, 2, pG + l * 4096, o & 4095);
    } else if (i < 40960) packOne(oW1, 64, 2, pO1u, i - 36864);   // rows 0..63
    else if (i < 43008) packOne(oW2, 32, 2, pOW2, i - 40960);
}

// -------- fused stage 1: MFMA MLP+z0 || (deg + bucket fill) || prep ----------
__global__ void __launch_bounds__(256)
k_fused1(const float* __restrict__ x,
         const ushort* __restrict__ pA, const float* __restrict__ fab1,
         const ushort* __restrict__ pB, const float* __restrict__ fab2,
         const ushort* __restrict__ pC, const float* __restrict__ projb,
         const ushort* __restrict__ pWz0,
         const float* __restrict__ asrc, const float* __restrict__ adst,
         uint* __restrict__ zbuf, float* __restrict__ es, float* __restrict__ ed,
         int N,
         const int* __restrict__ ei, int E,
         float* __restrict__ deg, int* __restrict__ cursor, int* __restrict__ esrc,
         const float* __restrict__ seW2, const float* __restrict__ seb2,
         const float* __restrict__ oW1, const float* __restrict__ ob1,
         float* __restrict__ M2, float* __restrict__ b2f, ushort* __restrict__ pM2f,
         int gMlp, int gEdge) {
    __shared__ ushort S[4][16][136];                   // bf16 staging, 17.4KB
    int bid = blockIdx.x;
    if (bid < gMlp) {
        int wave = threadIdx.x >> 6, lane = threadIdx.x & 63;
        int qg = lane >> 4, lr = lane & 15;
        int n0w = (bid * 4 + wave) * 16;
        int nr = n0w + lr; if (nr >= N) nr = N - 1;
        const float* xr = x + (size_t)nr * 128;
        ushort (*T)[136] = S[wave];
        const bf16x8* fA = reinterpret_cast<const bf16x8*>(pA);
        const bf16x8* fB = reinterpret_cast<const bf16x8*>(pB);
        const bf16x8* fC = reinterpret_cast<const bf16x8*>(pC);
        const bf16x8* fZ = reinterpret_cast<const bf16x8*>(pWz0);

        // ---- stage A: T = relu(X @ faW1 + b1) ----
        bf16x8 afr[4];
#pragma unroll
        for (int ks = 0; ks < 4; ++ks) {
            const float* p = xr + 32 * ks + 8 * qg;
            float4 v0 = *reinterpret_cast<const float4*>(p);
            float4 v1 = *reinterpret_cast<const float4*>(p + 4);
            bf16x8 a;
            a[0] = (short)f2bf(v0.x); a[1] = (short)f2bf(v0.y);
            a[2] = (short)f2bf(v0.z); a[3] = (short)f2bf(v0.w);
            a[4] = (short)f2bf(v1.x); a[5] = (short)f2bf(v1.y);
            a[6] = (short)f2bf(v1.z); a[7] = (short)f2bf(v1.w);
            afr[ks] = a;
        }
        {
            f32x4 acc[4] = {{0,0,0,0},{0,0,0,0},{0,0,0,0},{0,0,0,0}};
#pragma unroll
            for (int ct = 0; ct < 4; ++ct)
#pragma unroll
                for (int ks = 0; ks < 4; ++ks)
                    acc[ct] = __builtin_amdgcn_mfma_f32_16x16x32_bf16(
                        afr[ks], fA[(ct * 4 + ks) * 64 + lane], acc[ct], 0, 0, 0);
#pragma unroll
            for (int ct = 0; ct < 4; ++ct) {
                float b1v = fab1[ct * 16 + lr];
#pragma unroll
                for (int r = 0; r < 4; ++r)
                    T[qg * 4 + r][ct * 16 + lr] =
                        (ushort)f2bf(fmaxf(acc[ct][r] + b1v, 0.f));
            }
        }
        __syncthreads();

        // ---- stage B: F = T @ faW2 + b2 ----
        bf16x8 bfr[2];
#pragma unroll
        for (int ks = 0; ks < 2; ++ks)
            bfr[ks] = *reinterpret_cast<const bf16x8*>(&T[lr][32 * ks + 8 * qg]);
        __syncthreads();
        {
            f32x4 acc[8] = {{0,0,0,0},{0,0,0,0},{0,0,0,0},{0,0,0,0},
                            {0,0,0,0},{0,0,0,0},{0,0,0,0},{0,0,0,0}};
#pragma unroll
            for (int ct = 0; ct < 8; ++ct)
#pragma unroll
                for (int ks = 0; ks < 2; ++ks)
                    acc[ct] = __builtin_amdgcn_mfma_f32_16x16x32_bf16(
                        bfr[ks], fB[(ct * 2 + ks) * 64 + lane], acc[ct], 0, 0, 0);
#pragma unroll
            for (int ct = 0; ct < 8; ++ct) {
                float b2v = fab2[ct * 16 + lr];
#pragma unroll
                for (int r = 0; r < 4; ++r)
                    T[qg * 4 + r][ct * 16 + lr] = (ushort)f2bf(acc[ct][r] + b2v);
            }
        }
        __syncthreads();

        // ---- stage C: H = (X * sigmoid(F)) @ projW + projb -> T (bf16) ----
        bf16x8 cfr[4];
#pragma unroll
        for (int ks = 0; ks < 4; ++ks) {
            const ushort* pf = &T[lr][32 * ks + 8 * qg];
            const float* px = xr + 32 * ks + 8 * qg;
            float4 x0 = *reinterpret_cast<const float4*>(px);
            float4 x1 = *reinterpret_cast<const float4*>(px + 4);
            bf16x8 a;
            a[0] = (short)f2bf(x0.x / (1.f + __expf(-b2f16(pf[0]))));
            a[1] = (short)f2bf(x0.y / (1.f + __expf(-b2f16(pf[1]))));
            a[2] = (short)f2bf(x0.z / (1.f + __expf(-b2f16(pf[2]))));
            a[3] = (short)f2bf(x0.w / (1.f + __expf(-b2f16(pf[3]))));
            a[4] = (short)f2bf(x1.x / (1.f + __expf(-b2f16(pf[4]))));
            a[5] = (short)f2bf(x1.y / (1.f + __expf(-b2f16(pf[5]))));
            a[6] = (short)f2bf(x1.z / (1.f + __expf(-b2f16(pf[6]))));
            a[7] = (short)f2bf(x1.w / (1.f + __expf(-b2f16(pf[7]))));
            cfr[ks] = a;
        }
        __syncthreads();                               // F reads done before H write
        {
            f32x4 acc[4] = {{0,0,0,0},{0,0,0,0},{0,0,0,0},{0,0,0,0}};
#pragma unroll
            for (int ct = 0; ct < 4; ++ct)
#pragma unroll
                for (int ks = 0; ks < 4; ++ks)
                    acc[ct] = __builtin_amdgcn_mfma_f32_16x16x32_bf16(
                        cfr[ks], fC[(ct * 4 + ks) * 64 + lane], acc[ct], 0, 0, 0);
#pragma unroll
            for (int ct = 0; ct < 4; ++ct) {
                float pbv = projb[ct * 16 + lr];
#pragma unroll
                for (int r = 0; r < 4; ++r)
                    T[qg * 4 + r][ct * 16 + lr] = (ushort)f2bf(acc[ct][r] + pbv);
            }
        }
        __syncthreads();

        // ---- stage D: z0 = H @ W0 (8 MFMAs), es/ed + bf16 zbuf ----
        bf16x8 hfr[2];
#pragma unroll
        for (int ks = 0; ks < 2; ++ks)
            hfr[ks] = *reinterpret_cast<const bf16x8*>(&T[lr][32 * ks + 8 * qg]);
        __syncthreads();
        {
            f32x4 zacc[4] = {{0,0,0,0},{0,0,0,0},{0,0,0,0},{0,0,0,0}};
#pragma unroll
            for (int ct = 0; ct < 4; ++ct)
#pragma unroll
                for (int ks = 0; ks < 2; ++ks)
                    zacc[ct] = __builtin_amdgcn_mfma_f32_16x16x32_bf16(
                        hfr[ks], fZ[(ct * 2 + ks) * 64 + lane], zacc[ct], 0, 0, 0);
#pragma unroll
            for (int ct = 0; ct < 4; ++ct)
#pragma unroll
                for (int r = 0; r < 4; ++r)
                    T[qg * 4 + r][ct * 16 + lr] = (ushort)f2bf(zacc[ct][r]);
        }
        __syncthreads();
        {
            bf16x8 z0 = *reinterpret_cast<const bf16x8*>(&T[lr][qg * 16]);
            bf16x8 z1 = *reinterpret_cast<const bf16x8*>(&T[lr][qg * 16 + 8]);
            float pe = 0.f, pd = 0.f;
#pragma unroll
            for (int j = 0; j < 8; ++j) {
                float va = b2f16((ushort)z0[j]), vb = b2f16((ushort)z1[j]);
                pe = fmaf(va, asrc[qg * 16 + j], pe);
                pe = fmaf(vb, asrc[qg * 16 + 8 + j], pe);
                pd = fmaf(va, adst[qg * 16 + j], pd);
                pd = fmaf(vb, adst[qg * 16 + 8 + j], pd);
            }
            pe += __shfl_xor(pe, 16, 64); pe += __shfl_xor(pe, 32, 64);
            pd += __shfl_xor(pd, 16, 64); pd += __shfl_xor(pd, 32, 64);
            int n = n0w + lr;
            if (n < N) {
                uint4 u0, u1;
                u0.x = (ushort)z0[0] | ((uint)(ushort)z0[1] << 16);
                u0.y = (ushort)z0[2] | ((uint)(ushort)z0[3] << 16);
                u0.z = (ushort)z0[4] | ((uint)(ushort)z0[5] << 16);
                u0.w = (ushort)z0[6] | ((uint)(ushort)z0[7] << 16);
                u1.x = (ushort)z1[0] | ((uint)(ushort)z1[1] << 16);
                u1.y = (ushort)z1[2] | ((uint)(ushort)z1[3] << 16);
                u1.z = (ushort)z1[4] | ((uint)(ushort)z1[5] << 16);
                u1.w = (ushort)z1[6] | ((uint)(ushort)z1[7] << 16);
                uint* zr8 = zbuf + (size_t)n * 32 + qg * 8;
                *reinterpret_cast<uint4*>(zr8) = u0;
                *reinterpret_cast<uint4*>(zr8 + 4) = u1;
                if (qg == 0) { es[n] = pe; ed[n] = pd; esrc[(size_t)n * 64] = n; }
            }
        }
    } else if (bid < gMlp + gEdge) {
        int e = (bid - gMlp) * blockDim.x + threadIdx.x;
        if (e < E) {
            int s = ei[e], d = ei[E + e];
            atomicAdd(&deg[s], 1.f);
            int p = atomicAdd(&cursor[d], 1);
            esrc[(size_t)d * 64 + 1 + p] = s;
        }
    } else {
        int tid = threadIdx.x;
        for (int o = tid; o < 32 * 64; o += 256) {
            int k = o >> 6, j = o & 63;
            float s = 0.f;
            for (int i = 0; i < 64; ++i)
                s = fmaf(seW2[k * 64 + i], oW1[(64 + i) * 64 + j], s);
            M2[o] = s;
        }
        for (int j = tid; j < 64; j += 256) {
            float s = ob1[j];
            for (int i = 0; i < 64; ++i)
                s = fmaf(seb2[i], oW1[(64 + i) * 64 + j], s);
            b2f[j] = s;
        }
        __syncthreads();
        for (int o = tid; o < 2048; o += 256)
            packOne(M2, 64, 1, pM2f, o);
    }
}

// ---------------- MFMA GAT z (layers 1,2); || infl/scal rider ----------------
__global__ __attribute__((amdgpu_waves_per_eu(4, 4))) void __launch_bounds__(256)
k_z(const float* __restrict__ hbuf, const ushort* __restrict__ pWz,
    const float* __restrict__ asrc, const float* __restrict__ adst,
    uint* __restrict__ zbuf, float* __restrict__ es, float* __restrict__ ed,
    const float* __restrict__ deg, const float* __restrict__ inflsum,
    float* __restrict__ inflv, unsigned* __restrict__ scal,
    int N, int gZ) {
    int bid = blockIdx.x;
    if (bid >= gZ) {
        int idx = (bid - gZ) * blockDim.x + threadIdx.x;
        float dv = 0.f, iv = 0.f;
        if (idx < N) {
            dv = deg[idx];
            iv = dv > 0.f ? inflsum[idx] / dv : 0.f;
            inflv[idx] = iv;
        }
        float dm = dv, im = iv;
#pragma unroll
        for (int off = 32; off; off >>= 1) {
            dm = fmaxf(dm, __shfl_xor(dm, off, 64));
            im = fmaxf(im, __shfl_xor(im, off, 64));
        }
        if ((threadIdx.x & 63) == 0) {
            atomicMax(scal + 0, __float_as_uint(dm));
            atomicMax(scal + 1, __float_as_uint(im));
        }
        return;
    }
    __shared__ float zt[4][16][68];
    int wave = threadIdx.x >> 6, lane = threadIdx.x & 63;
    int qg = lane >> 4, lr = lane & 15;
    int n0w = (bid * 4 + wave) * 16;
    int nr = n0w + lr; if (nr >= N) nr = N - 1;

    bf16x8 afr[2];
#pragma unroll
    for (int k2 = 0; k2 < 2; ++k2) {
        const float* hp = hbuf + (size_t)nr * 64 + k2 * 32 + qg * 8;
        float4 h0 = *reinterpret_cast<const float4*>(hp);
        float4 h1 = *reinterpret_cast<const float4*>(hp + 4);
        bf16x8 a;
        a[0] = (short)f2bf(h0.x); a[1] = (short)f2bf(h0.y);
        a[2] = (short)f2bf(h0.z); a[3] = (short)f2bf(h0.w);
        a[4] = (short)f2bf(h1.x); a[5] = (short)f2bf(h1.y);
        a[6] = (short)f2bf(h1.z); a[7] = (short)f2bf(h1.w);
        afr[k2] = a;
    }

    const bf16x8* pw = reinterpret_cast<const bf16x8*>(pWz);
    f32x4 acc0 = {0,0,0,0}, acc1 = {0,0,0,0}, acc2 = {0,0,0,0}, acc3 = {0,0,0,0};
#pragma unroll
    for (int k2 = 0; k2 < 2; ++k2) {
        acc0 = __builtin_amdgcn_mfma_f32_16x16x32_bf16(afr[k2], pw[(0 * 2 + k2) * 64 + lane], acc0, 0, 0, 0);
        acc1 = __builtin_amdgcn_mfma_f32_16x16x32_bf16(afr[k2], pw[(1 * 2 + k2) * 64 + lane], acc1, 0, 0, 0);
        acc2 = __builtin_amdgcn_mfma_f32_16x16x32_bf16(afr[k2], pw[(2 * 2 + k2) * 64 + lane], acc2, 0, 0, 0);
        acc3 = __builtin_amdgcn_mfma_f32_16x16x32_bf16(afr[k2], pw[(3 * 2 + k2) * 64 + lane], acc3, 0, 0, 0);
    }

    float (*Z)[68] = zt[wave];
#pragma unroll
    for (int r = 0; r < 4; ++r) {
        Z[qg * 4 + r][0 * 16 + lr] = acc0[r];
        Z[qg * 4 + r][1 * 16 + lr] = acc1[r];
        Z[qg * 4 + r][2 * 16 + lr] = acc2[r];
        Z[qg * 4 + r][3 * 16 + lr] = acc3[r];
    }
    __syncthreads();

    float zr[16];
    const float* zrow = &Z[lr][qg * 16];
#pragma unroll
    for (int q4 = 0; q4 < 4; ++q4) {
        float4 v = *reinterpret_cast<const float4*>(zrow + q4 * 4);
        zr[q4 * 4] = v.x; zr[q4 * 4 + 1] = v.y; zr[q4 * 4 + 2] = v.z; zr[q4 * 4 + 3] = v.w;
    }
    float pe = 0.f, pd = 0.f;
#pragma unroll
    for (int j = 0; j < 16; ++j) {
        pe = fmaf(zr[j], asrc[qg * 16 + j], pe);
        pd = fmaf(zr[j], adst[qg * 16 + j], pd);
    }
    pe += __shfl_xor(pe, 16, 64); pe += __shfl_xor(pe, 32, 64);
    pd += __shfl_xor(pd, 16, 64); pd += __shfl_xor(pd, 32, 64);

    int n = n0w + lr;
    if (n < N) {
        uint4 u0, u1;
        u0.x = f2bf(zr[0]) | (f2bf(zr[1]) << 16);
        u0.y = f2bf(zr[2]) | (f2bf(zr[3]) << 16);
        u0.z = f2bf(zr[4]) | (f2bf(zr[5]) << 16);
        u0.w = f2bf(zr[6]) | (f2bf(zr[7]) << 16);
        u1.x = f2bf(zr[8]) | (f2bf(zr[9]) << 16);
        u1.y = f2bf(zr[10]) | (f2bf(zr[11]) << 16);
        u1.z = f2bf(zr[12]) | (f2bf(zr[13]) << 16);
        u1.w = f2bf(zr[14]) | (f2bf(zr[15]) << 16);
        uint* zr8 = zbuf + (size_t)n * 32 + qg * 8;
        *reinterpret_cast<uint4*>(zr8) = u0;
        *reinterpret_cast<uint4*>(zr8 + 4) = u1;
        if (qg == 0) { es[n] = pe; ed[n] = pd; }
    }
}

// -------- fused GAT aggregation: quad-edge quarter-wave; || inflsum rider ----
__global__ void k_agg(const int* __restrict__ cursor,
                      const int* __restrict__ esrc,
                      const float* __restrict__ es, const float* __restrict__ ed,
                      const uint* __restrict__ zb,
                      const float* __restrict__ b, const float* __restrict__ g,
                      const float* __restrict__ bta, const float* __restrict__ mean,
                      const float* __restrict__ var,
                      float* __restrict__ hbuf, int N,
                      const int* __restrict__ ei, int E,
                      const float* __restrict__ deg, float* __restrict__ inflsum,
                      int gAgg) {
    if (blockIdx.x >= gAgg) {
        int e = (blockIdx.x - gAgg) * blockDim.x + threadIdx.x;
        if (e < E) atomicAdd(&inflsum[ei[e]], deg[ei[E + e]]);
        return;
    }
    int wid  = (blockIdx.x * blockDim.x + threadIdx.x) >> 6;
    int lane = threadIdx.x & 63;
    if (wid >= N) return;
    size_t row0 = (size_t)wid * 64;
    int c    = cursor[wid] + 1;    // +1 self-loop; c <= 64 guaranteed
    float edn = ed[wid];
    int lq = lane & 15, q = lane >> 4;

    int   sreg = 0;
    float exv  = 0.f;
    if (lane < c) {
        sreg = esrc[row0 + lane];                      // coalesced 256B row
        float e = es[sreg] + edn;
        e = e >= 0.f ? e : 0.2f * e;
        exv = __expf(e);
    }
    float ssum = exv;
#pragma unroll
    for (int off = 32; off; off >>= 1) ssum += __shfl_xor(ssum, off, 64);

    float a0 = 0.f, a1 = 0.f, a2 = 0.f, a3 = 0.f;
    for (int e = q; e < c; e += 4) {
        int   se = __shfl(sreg, e, 64);
        float we = __shfl(exv, e, 64);
        uint2 p = *reinterpret_cast<const uint2*>(zb + (size_t)se * 32 + lq * 2);
        a0 = fmaf(bflo(p.x), we, a0);
        a1 = fmaf(bfhi(p.x), we, a1);
        a2 = fmaf(bflo(p.y), we, a2);
        a3 = fmaf(bfhi(p.y), we, a3);
    }
    a0 += __shfl_xor(a0, 16, 64); a0 += __shfl_xor(a0, 32, 64);
    a1 += __shfl_xor(a1, 16, 64); a1 += __shfl_xor(a1, 32, 64);
    a2 += __shfl_xor(a2, 16, 64); a2 += __shfl_xor(a2, 32, 64);
    a3 += __shfl_xor(a3, 16, 64); a3 += __shfl_xor(a3, 32, 64);

    if (q == 0) {
        float inv = 1.f / ssum;
        float4 bb = reinterpret_cast<const float4*>(b)[lq];
        float4 gg = reinterpret_cast<const float4*>(g)[lq];
        float4 tt = reinterpret_cast<const float4*>(bta)[lq];
        float4 mm = reinterpret_cast<const float4*>(mean)[lq];
        float4 vv = reinterpret_cast<const float4*>(var)[lq];
        float v0 = (a0 * inv + bb.x - mm.x) * (gg.x * rsqrtf(vv.x + 1e-5f)) + tt.x;
        float v1 = (a1 * inv + bb.y - mm.y) * (gg.y * rsqrtf(vv.y + 1e-5f)) + tt.y;
        float v2 = (a2 * inv + bb.z - mm.z) * (gg.z * rsqrtf(vv.z + 1e-5f)) + tt.z;
        float v3 = (a3 * inv + bb.w - mm.w) * (gg.w * rsqrtf(vv.w + 1e-5f)) + tt.w;
        reinterpret_cast<float4*>(hbuf + (size_t)wid * 64)[lq] =
            make_float4(fmaxf(v0, 0.f), fmaxf(v1, 0.f), fmaxf(v2, 0.f), fmaxf(v3, 0.f));
    }
}

// ---------------- MFMA output head: 16 nodes/wave ----------------
__global__ void __launch_bounds__(256)
k_final(const float* __restrict__ hbuf, const float* __restrict__ deg,
        const float* __restrict__ inflv, const unsigned* __restrict__ scal,
        const float* __restrict__ seW1, const float* __restrict__ seb1,
        const ushort* __restrict__ pM2f, const float* __restrict__ b2f,
        const ushort* __restrict__ pO1u, const ushort* __restrict__ pOW2,
        const float* __restrict__ ob2,
        const float* __restrict__ oW3, const float* __restrict__ ob3,
        float* __restrict__ out, int N) {
    __shared__ ushort S[4][16][136];
    int wave = threadIdx.x >> 6, lane = threadIdx.x & 63;
    int qg = lane >> 4, lr = lane & 15;
    int n0w = (blockIdx.x * 4 + wave) * 16;
    int nr = n0w + lr; if (nr >= N) nr = N - 1;
    ushort (*T)[136] = S[wave];

    float degmax  = fmaxf(__uint_as_float(scal[0]), 1.0f);
    float inflmax = fmaxf(__uint_as_float(scal[1]), 1e-12f);
    float nd = deg[nr] / degmax;
    float fl = inflv[nr] / inflmax;

    bf16x8 a0, a1, a2;
#pragma unroll
    for (int ks = 0; ks < 2; ++ks) {
        const float* hp = hbuf + (size_t)nr * 64 + 32 * ks + 8 * qg;
        float4 h0 = *reinterpret_cast<const float4*>(hp);
        float4 h1 = *reinterpret_cast<const float4*>(hp + 4);
        bf16x8 a;
        a[0] = (short)f2bf(h0.x); a[1] = (short)f2bf(h0.y);
        a[2] = (short)f2bf(h0.z); a[3] = (short)f2bf(h0.w);
        a[4] = (short)f2bf(h1.x); a[5] = (short)f2bf(h1.y);
        a[6] = (short)f2bf(h1.z); a[7] = (short)f2bf(h1.w);
        if (ks == 0) a0 = a; else a1 = a;
    }
#pragma unroll
    for (int j = 0; j < 8; ++j) {
        int k = 8 * qg + j;
        float hid = fmaxf(fmaf(nd, seW1[k], fmaf(fl, seW1[64 + k], seb1[k])), 0.f);
        a2[j] = (short)f2bf(hid);
    }

    const bf16x8* fO1 = reinterpret_cast<const bf16x8*>(pO1u);
    const bf16x8* fM2 = reinterpret_cast<const bf16x8*>(pM2f);
    const bf16x8* fW2 = reinterpret_cast<const bf16x8*>(pOW2);

    {
        f32x4 acc[4] = {{0,0,0,0},{0,0,0,0},{0,0,0,0},{0,0,0,0}};
#pragma unroll
        for (int ct = 0; ct < 4; ++ct) {
            acc[ct] = __builtin_amdgcn_mfma_f32_16x16x32_bf16(a0, fO1[(ct * 2 + 0) * 64 + lane], acc[ct], 0, 0, 0);
            acc[ct] = __builtin_amdgcn_mfma_f32_16x16x32_bf16(a1, fO1[(ct * 2 + 1) * 64 + lane], acc[ct], 0, 0, 0);
            acc[ct] = __builtin_amdgcn_mfma_f32_16x16x32_bf16(a2, fM2[ct * 64 + lane], acc[ct], 0, 0, 0);
        }
#pragma unroll
        for (int ct = 0; ct < 4; ++ct) {
            float bv = b2f[ct * 16 + lr];
#pragma unroll
            for (int r = 0; r < 4; ++r)
                T[qg * 4 + r][ct * 16 + lr] =
                    (ushort)f2bf(fmaxf(acc[ct][r] + bv, 0.f));
        }
    }
    __syncthreads();

    bf16x8 b0 = *reinterpret_cast<const bf16x8*>(&T[lr][8 * qg]);
    bf16x8 b1 = *reinterpret_cast<const bf16x8*>(&T[lr][32 + 8 * qg]);
    f32x4 o2a = {0,0,0,0}, o2b = {0,0,0,0};
    o2a = __builtin_amdgcn_mfma_f32_16x16x32_bf16(b0, fW2[0 * 64 + lane], o2a, 0, 0, 0);
    o2a = __builtin_amdgcn_mfma_f32_16x16x32_bf16(b1, fW2[1 * 64 + lane], o2a, 0, 0, 0);
    o2b = __builtin_amdgcn_mfma_f32_16x16x32_bf16(b0, fW2[2 * 64 + lane], o2b, 0, 0, 0);
    o2b = __builtin_amdgcn_mfma_f32_16x16x32_bf16(b1, fW2[3 * 64 + lane], o2b, 0, 0, 0);

    float w3a = oW3[lr], w3b = oW3[16 + lr];
    float oba = ob2[lr], obb = ob2[16 + lr];
    float part[4];
#pragma unroll
    for (int r = 0; r < 4; ++r)
        part[r] = fmaxf(o2a[r] + oba, 0.f) * w3a + fmaxf(o2b[r] + obb, 0.f) * w3b;
#pragma unroll
    for (int off = 1; off < 16; off <<= 1) {
#pragma unroll
        for (int r = 0; r < 4; ++r) part[r] += __shfl_xor(part[r], off, 64);
    }
    if (lr == 0) {
        float b3 = ob3[0];
#pragma unroll
        for (int r = 0; r < 4; ++r) {
            int n = n0w + qg * 4 + r;
            if (n < N) out[n] = 1.f / (1.f + __expf(-(part[r] + b3)));
        }
    }
}

// ---------------- launch ----------------
extern "C" void kernel_launch(void* const* d_in, const int* in_sizes, int n_in,
                              void* d_out, int out_size, void* d_ws, size_t ws_size,
                              hipStream_t stream) {
    const float* x     = (const float*)d_in[0];
    const int*   ei    = (const int*)d_in[1];
    const float* faW1  = (const float*)d_in[2];
    const float* fab1  = (const float*)d_in[3];
    const float* faW2  = (const float*)d_in[4];
    const float* fab2  = (const float*)d_in[5];
    const float* projW = (const float*)d_in[6];
    const float* projb = (const float*)d_in[7];
    const float* gatW  = (const float*)d_in[8];
    const float* gatAs = (const float*)d_in[9];
    const float* gatAd = (const float*)d_in[10];
    const float* gatB  = (const float*)d_in[11];
    const float* bnG   = (const float*)d_in[12];
    const float* bnB   = (const float*)d_in[13];
    const float* bnM   = (const float*)d_in[14];
    const float* bnV   = (const float*)d_in[15];
    const float* seW1  = (const float*)d_in[16];
    const float* seb1  = (const float*)d_in[17];
    const float* seW2  = (const float*)d_in[18];
    const float* seb2  = (const float*)d_in[19];
    const float* oW1   = (const float*)d_in[20];
    const float* ob1   = (const float*)d_in[21];
    const float* oW2   = (const float*)d_in[22];
    const float* ob2   = (const float*)d_in[23];
    const float* oW3   = (const float*)d_in[24];
    const float* ob3   = (const float*)d_in[25];
    float* out = (float*)d_out;

    const int N = in_sizes[0] / 128;
    const int E = in_sizes[1] / 2;

    float* ws      = (float*)d_ws;
    float* hbuf    = ws;                               // N*64
    uint*  zbuf    = (uint*)(hbuf + (size_t)N * 64);   // N*32 (bf16 pairs)
    float* es      = (float*)(zbuf + (size_t)N * 32);  // N
    float* ed      = es + N;                           // N
    // ---- zero region (one memset: 3N+8 dwords) ----
    float* deg     = ed + N;                           // N
    float* inflsum = deg + N;                          // N
    unsigned* scal = (unsigned*)(inflsum + N);         // 8
    int* cursor    = (int*)(scal + 8);                 // N
    // ---- end zero region ----
    float* inflv   = (float*)(cursor + N);             // N
    int* esrc      = (int*)(inflv + N);                // N*64 padded buckets
    float* M2      = (float*)(esrc + (size_t)N * 64);  // 32*64
    float* b2f     = M2 + 32 * 64;                     // 64
    ushort* pA   = (ushort*)(b2f + 64);                // 8192
    ushort* pB   = pA + 8192;                          // 8192
    ushort* pC   = pB + 8192;                          // 8192
    ushort* pWz  = pC + 8192;                          // 3*4096
    ushort* pO1u = pWz + 3 * 4096;                     // 4096
    ushort* pOW2 = pO1u + 4096;                        // 2048
    ushort* pM2f = pOW2 + 2048;                        // 2048

    dim3 blk(256);
    int gN    = (N + 255) / 256;
    int gE    = (E + 255) / 256;
    int gM    = (N + 63) / 64;                         // MFMA tiles: 64 nodes/block
    int blkNW = (N * 64 + 255) / 256;                  // wave-per-node (k_agg)

    hipMemsetAsync(deg, 0, ((size_t)3 * N + 8) * sizeof(float), stream);

    // stage 0: pack static MFMA weight fragments
    k_pack<<<168, blk, 0, stream>>>(faW1, faW2, projW, gatW, oW1, oW2,
                                    pA, pB, pC, pWz, pO1u, pOW2);

    // stage 1: MFMA mlp+z0 || (deg + bucket fill) || prep(+M2 frag)
    k_fused1<<<gM + gE + 1, blk, 0, stream>>>(x, pA, fab1, pB, fab2, pC, projb,
                                              pWz, gatAs, gatAd, zbuf, es, ed, N,
                                              ei, E, deg, cursor, esrc,
                                              seW2, seb2, oW1, ob1, M2, b2f, pM2f,
                                              gM, gE);

    for (int l = 0; l < 3; ++l) {
        int aggExtra = (l == 0) ? gE : 0;              // inflsum rider on l==0
        k_agg<<<blkNW + aggExtra, blk, 0, stream>>>(cursor, esrc, es, ed, zbuf,
                                                    gatB + l * 64, bnG + l * 64,
                                                    bnB + l * 64, bnM + l * 64,
                                                    bnV + l * 64, hbuf, N,
                                                    ei, E, deg, inflsum, blkNW);
        if (l < 2) {
            int extra = (l == 0) ? gN : 0;             // infl/scal reduce on first k_z
            k_z<<<gM + extra, blk, 0, stream>>>(hbuf, pWz + (l + 1) * 4096,
                                                gatAs + (l + 1) * 64,
                                                gatAd + (l + 1) * 64,
                                                zbuf, es, ed,
                                                deg, inflsum, inflv, scal, N, gM);
        }
    }

    k_final<<<gM, blk, 0, stream>>>(hbuf, deg, inflv, scal, seW1, seb1,
                                    pM2f, b2f, pO1u, pOW2, ob2, oW3, ob3, out, N);
}